// Round 6
// baseline (363.942 us; speedup 1.0000x reference)
//
#include <hip/hip_runtime.h>
#include <hip/hip_bf16.h>
#include <math.h>

// ---------------------------------------------------------------------------
// CrossModalityMultiHeadAttention  (MI355X / gfx950)
// Round 6:
//   - gemm128: register-prefetch pipeline (distance 2) -> ds_write_b128
//     staging; kills the per-iteration vmcnt(0) full-latency drain that made
//     round-5's global_load_lds version latency-bound at K=512
//   - map GEMM folded into head projections via fused weights
//     FW = map_w @ x1_w (computed on device), fb = map_b @ x1_w + x1_b
//     -> all 6 projections in ONE z=6 dispatch (768 blocks, 3/CU)
//   - dispatches: prep, transpose(8), fuseW(z=3), proj(z=6), attn(z=2),
//     out(z=2) = 6 total
// ---------------------------------------------------------------------------

typedef __bf16 bf16x8 __attribute__((ext_vector_type(8)));
typedef float  f32x4  __attribute__((ext_vector_type(4)));

#define HID 512
#define NTOK 4096
#define KHEAD 384   // 300 padded

// --------------------------- input prep ------------------------------------
// grid (512,1,3), 256 thr.
//  z=0: head conv [4096,300]fp32 -> [4096,384]bf16 (+ranges on block 0)
//  z=1: tail conv [4096,512]fp32 -> [4096,512]bf16
//  z=2: q<96: map_w -> map_bf [384][512] bf16 (rows 300.. zero)
//       q in [96,102): fused biases fb_x = map_b @ x1_w + x1_b
//       q==102: zbuf = 0 (bias for fuseW gemm)
__global__ __launch_bounds__(256) void prep_inputs(
    const float* __restrict__ h_head, const float* __restrict__ h_tail,
    const int* __restrict__ bh, const int* __restrict__ bt,
    const float* __restrict__ map_w, const float* __restrict__ map_b,
    const float* __restrict__ q1_w, const float* __restrict__ q1_b,
    const float* __restrict__ k1_w, const float* __restrict__ k1_b,
    const float* __restrict__ v1_w, const float* __restrict__ v1_b,
    __bf16* __restrict__ hh_bf, __bf16* __restrict__ ht_bf,
    __bf16* __restrict__ map_bf,
    float* __restrict__ fb, float* __restrict__ zbuf,
    int* __restrict__ ranges)
{
    const int q = blockIdx.x, z = blockIdx.z, tid = threadIdx.x;

    if (z == 0) {
        if (q == 0 && tid < 128) {
            int b = tid & 63;
            const int* arr = (tid < 64) ? bh : bt;
            int base = (tid < 64) ? 0 : 128;
            int lo = 0, hi = NTOK;
            while (lo < hi) { int mid = (lo + hi) >> 1; if (arr[mid] < b) lo = mid + 1; else hi = mid; }
            int start = lo;
            lo = 0; hi = NTOK;
            while (lo < hi) { int mid = (lo + hi) >> 1; if (arr[mid] <= b) lo = mid + 1; else hi = mid; }
            ranges[base + b] = start;
            ranges[base + 64 + b] = lo;
        }
        // head: 8 rows x 48 chunks = 384
        for (int idx = tid; idx < 8 * 48; idx += 256) {
            int r   = q * 8 + idx / 48;
            int col = (idx % 48) * 8;
            bf16x8 v;
            if (col + 8 <= 300) {
                float4 f0 = *(const float4*)&h_head[(size_t)r * 300 + col];
                float4 f1 = *(const float4*)&h_head[(size_t)r * 300 + col + 4];
                v[0]=(__bf16)f0.x; v[1]=(__bf16)f0.y; v[2]=(__bf16)f0.z; v[3]=(__bf16)f0.w;
                v[4]=(__bf16)f1.x; v[5]=(__bf16)f1.y; v[6]=(__bf16)f1.z; v[7]=(__bf16)f1.w;
            } else if (col < 300) {  // col == 296
                float4 f0 = *(const float4*)&h_head[(size_t)r * 300 + col];
                v[0]=(__bf16)f0.x; v[1]=(__bf16)f0.y; v[2]=(__bf16)f0.z; v[3]=(__bf16)f0.w;
                v[4]=(__bf16)0.f; v[5]=(__bf16)0.f; v[6]=(__bf16)0.f; v[7]=(__bf16)0.f;
            } else {
                #pragma unroll
                for (int j = 0; j < 8; ++j) v[j] = (__bf16)0.f;
            }
            *(bf16x8*)&hh_bf[(size_t)r * KHEAD + col] = v;
        }
    } else if (z == 1) {
        for (int idx = tid; idx < 8 * 64; idx += 256) {
            int r   = q * 8 + (idx >> 6);
            int col = (idx & 63) * 8;
            float4 f0 = *(const float4*)&h_tail[(size_t)r * 512 + col];
            float4 f1 = *(const float4*)&h_tail[(size_t)r * 512 + col + 4];
            bf16x8 v;
            v[0]=(__bf16)f0.x; v[1]=(__bf16)f0.y; v[2]=(__bf16)f0.z; v[3]=(__bf16)f0.w;
            v[4]=(__bf16)f1.x; v[5]=(__bf16)f1.y; v[6]=(__bf16)f1.z; v[7]=(__bf16)f1.w;
            *(bf16x8*)&ht_bf[(size_t)r * 512 + col] = v;
        }
    } else {
        if (q < 96) {
            // map_bf rows q*4 .. q*4+3
            int r = q * 4 + (tid >> 6);
            int col = (tid & 63) * 8;
            bf16x8 v;
            if (r < 300) {
                float4 f0 = *(const float4*)&map_w[(size_t)r * 512 + col];
                float4 f1 = *(const float4*)&map_w[(size_t)r * 512 + col + 4];
                v[0]=(__bf16)f0.x; v[1]=(__bf16)f0.y; v[2]=(__bf16)f0.z; v[3]=(__bf16)f0.w;
                v[4]=(__bf16)f1.x; v[5]=(__bf16)f1.y; v[6]=(__bf16)f1.z; v[7]=(__bf16)f1.w;
            } else {
                #pragma unroll
                for (int j = 0; j < 8; ++j) v[j] = (__bf16)0.f;
            }
            *(bf16x8*)&map_bf[(size_t)r * 512 + col] = v;
        } else if (q < 102) {
            __shared__ float sm[512];
            sm[tid] = map_b[tid];
            sm[tid + 256] = map_b[tid + 256];
            __syncthreads();
            int m = q - 96;
            int x = m >> 1, half = m & 1;
            int n = half * 256 + tid;
            const float* xw = x == 0 ? q1_w : (x == 1 ? k1_w : v1_w);
            const float* xb = x == 0 ? q1_b : (x == 1 ? k1_b : v1_b);
            float s = xb[n];
            for (int j = 0; j < 512; ++j)
                s += sm[j] * xw[(size_t)j * 512 + n];
            fb[x * 512 + n] = s;
        } else if (q == 102) {
            zbuf[tid] = 0.f;
            zbuf[tid + 256] = 0.f;
        }
    }
}

// --------------------------- weight transpose ------------------------------
// W[512][512] fp32 -> WT[512][512] bf16; 8 jobs.
struct Trans8 {
    const float* src[8];
    __bf16*      dst[8];
};

__global__ __launch_bounds__(256) void transpose_weights(Trans8 tj) {
    const int z = blockIdx.z;
    const float* src = tj.src[z];
    __bf16* dst = tj.dst[z];
    const int tk = blockIdx.y * 64;
    const int tn = blockIdx.x * 64;

    __shared__ __bf16 T[64][72];
    const int tid = threadIdx.x;
    const int r0 = tid >> 4;
    const int c0 = (tid & 15) * 4;
    #pragma unroll
    for (int i = 0; i < 4; ++i) {
        int k = tk + r0 + i * 16;
        float4 v = *(const float4*)&src[(size_t)k * 512 + tn + c0];
        T[r0 + i * 16][c0 + 0] = (__bf16)v.x;
        T[r0 + i * 16][c0 + 1] = (__bf16)v.y;
        T[r0 + i * 16][c0 + 2] = (__bf16)v.z;
        T[r0 + i * 16][c0 + 3] = (__bf16)v.w;
    }
    __syncthreads();

    const int n  = tid >> 2;
    const int kk = (tid & 3) * 16;
    bf16x8 o0, o1;
    #pragma unroll
    for (int j = 0; j < 8; ++j) { o0[j] = T[kk + j][n]; o1[j] = T[kk + 8 + j][n]; }
    __bf16* dp = dst + (size_t)(tn + n) * 512 + tk + kk;
    *(bf16x8*)dp       = o0;
    *(bf16x8*)(dp + 8) = o1;
}

// ------------------------------ GEMM 128x128 -------------------------------
// C[M,N] = A[M,Kp]bf16 @ WT[N,Kp]bf16^T + bias[N]; z = job select.
// 256 thr = 4 waves (2x2), each wave 64x64 (4x4 16x16x32 frags).
// K-loop: distance-2 REGISTER prefetch -> ds_write_b128 staging. Loads for
// tile i+2 are issued after the staging barrier and fly across the whole
// MFMA section + next iteration, so the barrier drain waits on old loads.
struct GemmJobs {
    const __bf16* A[6];
    const __bf16* W[6];
    const float*  bias[6];
    void*         C[6];
    int           Kp[6];
    int           ldC[6];
};

template <typename TC>
__global__ __launch_bounds__(256, 3) void gemm128(GemmJobs jobs) {
    __shared__ __align__(16) __bf16 As[4096];   // [128][32]
    __shared__ __align__(16) __bf16 Bs[4096];

    const int z = blockIdx.z;
    const __bf16* A    = jobs.A[z];
    const __bf16* W    = jobs.W[z];
    const float*  bias = jobs.bias[z];
    TC*           C    = (TC*)jobs.C[z];
    const int     Kp   = jobs.Kp[z];
    const int     ldC  = jobs.ldC[z];

    const int tid  = threadIdx.x;
    const int wave = tid >> 6;
    const int lane = tid & 63;
    const int quad = lane >> 4;
    const int l16  = lane & 15;
    const int wy   = wave >> 1;
    const int wx   = wave & 1;
    const int rowBase = blockIdx.y * 128;
    const int colBase = blockIdx.x * 128;

    const int s_row = tid >> 2;           // 0..63
    const int s_kc  = (tid & 3) * 8;

    const __bf16* gA = A + (size_t)(rowBase + s_row) * Kp + s_kc;
    const __bf16* gB = W + (size_t)(colBase + s_row) * Kp + s_kc;

    f32x4 acc[4][4] = {};
    bf16x8 pa0[2], pa1[2], pb0[2], pb1[2];
    const int nk = Kp >> 5;

    #pragma unroll
    for (int s = 0; s < 2; ++s) {         // preload tiles 0,1
        int kt = s * 32;
        pa0[s] = *(const bf16x8*)(gA + kt);
        pa1[s] = *(const bf16x8*)(gA + kt + (size_t)64 * Kp);
        pb0[s] = *(const bf16x8*)(gB + kt);
        pb1[s] = *(const bf16x8*)(gB + kt + (size_t)64 * Kp);
    }

    for (int i = 0; i < nk; ++i) {
        const int cur = i & 1;
        if (i) __syncthreads();           // previous iteration's ds_reads done
        *(bf16x8*)&As[tid * 8]        = pa0[cur];
        *(bf16x8*)&As[2048 + tid * 8] = pa1[cur];
        *(bf16x8*)&Bs[tid * 8]        = pb0[cur];
        *(bf16x8*)&Bs[2048 + tid * 8] = pb1[cur];
        __syncthreads();                  // staging visible

        if (i + 2 < nk) {                 // prefetch tile i+2 (in flight ~1.5 iters)
            int kt = (i + 2) * 32;
            pa0[cur] = *(const bf16x8*)(gA + kt);
            pa1[cur] = *(const bf16x8*)(gA + kt + (size_t)64 * Kp);
            pb0[cur] = *(const bf16x8*)(gB + kt);
            pb1[cur] = *(const bf16x8*)(gB + kt + (size_t)64 * Kp);
        }

        bf16x8 ar[4], br[4];
        #pragma unroll
        for (int ii = 0; ii < 4; ++ii)
            ar[ii] = *(const bf16x8*)&As[(wy * 64 + ii * 16 + l16) * 32 + quad * 8];
        #pragma unroll
        for (int jj = 0; jj < 4; ++jj)
            br[jj] = *(const bf16x8*)&Bs[(wx * 64 + jj * 16 + l16) * 32 + quad * 8];
        #pragma unroll
        for (int ii = 0; ii < 4; ++ii)
            #pragma unroll
            for (int jj = 0; jj < 4; ++jj)
                acc[ii][jj] = __builtin_amdgcn_mfma_f32_16x16x32_bf16(ar[ii], br[jj], acc[ii][jj], 0, 0, 0);
    }

    #pragma unroll
    for (int jj = 0; jj < 4; ++jj) {
        int col = colBase + wx * 64 + jj * 16 + l16;
        float bv = bias[col];
        #pragma unroll
        for (int ii = 0; ii < 4; ++ii) {
            #pragma unroll
            for (int r = 0; r < 4; ++r) {
                int row = rowBase + wy * 64 + ii * 16 + quad * 4 + r;
                C[(size_t)row * ldC + col] = (TC)(acc[ii][jj][r] + bv);
            }
        }
    }
}

// ------------------------- MFMA flash attention ----------------------------
__global__ __launch_bounds__(256) void attn_mfma(
    const __bf16* __restrict__ Q0, const __bf16* __restrict__ K0,
    const __bf16* __restrict__ Vr0, const __bf16* __restrict__ Vc0,
    const __bf16* __restrict__ Q1, const __bf16* __restrict__ K1,
    const __bf16* __restrict__ Vr1, const __bf16* __restrict__ Vc1,
    const int* __restrict__ ranges,
    __bf16* __restrict__ O0, __bf16* __restrict__ O1,
    int Nq, int Nk)
{
    __shared__ __align__(16) __bf16 Qs[64][72];
    __shared__ __align__(16) __bf16 Ks[64][72];
    __shared__ __align__(16) __bf16 Vt[64][72];
    __shared__ __align__(16) __bf16 Ps[64][72];

    const int z = blockIdx.z;
    const __bf16* Q    = z ? Q1 : Q0;
    const __bf16* Kg   = z ? K1 : K0;
    const __bf16* Vres = z ? Vr1 : Vr0;
    const __bf16* Vctx = z ? Vc1 : Vc0;
    __bf16* Out        = z ? O1 : O0;
    const int* qstart  = z ? ranges + 128 : ranges;
    const int* qend    = z ? ranges + 192 : ranges + 64;
    const int* kstart  = z ? ranges       : ranges + 128;
    const int* kend    = z ? ranges + 64  : ranges + 192;

    const int h = blockIdx.x, b = blockIdx.y;
    const int qs = qstart[b], qe = qend[b];
    const int ts = kstart[b], te = kend[b];
    const int nq = qe - qs, nk = te - ts;
    if (nq <= 0) return;

    const int tid  = threadIdx.x;
    const int wave = tid >> 6;
    const int lane = tid & 63;
    const int quad = lane >> 4;
    const int l16  = lane & 15;
    const int srow = tid >> 2;
    const int scol = (tid & 3) * 16;

    if (nk <= 0) {
        float* meanv = (float*)Qs;
        if (tid < 64) {
            float s = 0.f;
            for (int m = 0; m < Nk; ++m)
                s += (float)Vctx[(size_t)m * HID + h * 64 + tid];
            meanv[tid] = s / (float)Nk;
        }
        __syncthreads();
        int d = tid & 63;
        for (int r = qs + (tid >> 6); r < qe; r += 4) {
            size_t off = (size_t)r * HID + h * 64 + d;
            Out[off] = (__bf16)((float)Vres[off] + meanv[d]);
        }
        return;
    }

    for (int qc = 0; qc < nq; qc += 64) {
        __syncthreads();
        {
            int qg = min(qs + qc + srow, Nq - 1);
            const __bf16* src = Q + (size_t)qg * HID + h * 64 + scol;
            *(bf16x8*)&Qs[srow][scol]     = *(const bf16x8*)src;
            *(bf16x8*)&Qs[srow][scol + 8] = *(const bf16x8*)(src + 8);
        }
        __syncthreads();
        bf16x8 aq0 = *(const bf16x8*)&Qs[wave * 16 + l16][quad * 8];
        bf16x8 aq1 = *(const bf16x8*)&Qs[wave * 16 + l16][32 + quad * 8];

        f32x4 O[4] = {};
        float Mx[4], L[4];
        #pragma unroll
        for (int r = 0; r < 4; ++r) { Mx[r] = -__builtin_inff(); L[r] = 0.f; }

        for (int kc = 0; kc < nk; kc += 64) {
            __syncthreads();
            {
                int kg = min(ts + kc + srow, Nk - 1);
                const __bf16* ksrc = Kg + (size_t)kg * HID + h * 64 + scol;
                *(bf16x8*)&Ks[srow][scol]     = *(const bf16x8*)ksrc;
                *(bf16x8*)&Ks[srow][scol + 8] = *(const bf16x8*)(ksrc + 8);
                const __bf16* vsrc = Vctx + (size_t)kg * HID + h * 64 + scol;
                bf16x8 v0 = *(const bf16x8*)vsrc;
                bf16x8 v1 = *(const bf16x8*)(vsrc + 8);
                #pragma unroll
                for (int j = 0; j < 8; ++j) {
                    Vt[scol + j][srow]     = v0[j];
                    Vt[scol + 8 + j][srow] = v1[j];
                }
            }
            __syncthreads();

            f32x4 S[4] = {};
            #pragma unroll
            for (int c = 0; c < 4; ++c) {
                bf16x8 bk0 = *(const bf16x8*)&Ks[c * 16 + l16][quad * 8];
                bf16x8 bk1 = *(const bf16x8*)&Ks[c * 16 + l16][32 + quad * 8];
                S[c] = __builtin_amdgcn_mfma_f32_16x16x32_bf16(aq0, bk0, S[c], 0, 0, 0);
                S[c] = __builtin_amdgcn_mfma_f32_16x16x32_bf16(aq1, bk1, S[c], 0, 0, 0);
            }

            #pragma unroll
            for (int c = 0; c < 4; ++c) {
                bool valid = (ts + kc + c * 16 + l16) < te;
                #pragma unroll
                for (int r = 0; r < 4; ++r)
                    S[c][r] = valid ? S[c][r] * 0.125f : -__builtin_inff();
            }

            float cm[4], ps[4], alpha[4];
            #pragma unroll
            for (int r = 0; r < 4; ++r) {
                float v = fmaxf(fmaxf(S[0][r], S[1][r]), fmaxf(S[2][r], S[3][r]));
                v = fmaxf(v, __shfl_xor(v, 1, 64));
                v = fmaxf(v, __shfl_xor(v, 2, 64));
                v = fmaxf(v, __shfl_xor(v, 4, 64));
                v = fmaxf(v, __shfl_xor(v, 8, 64));
                cm[r] = v;
            }
            #pragma unroll
            for (int r = 0; r < 4; ++r) {
                float nM = fmaxf(Mx[r], cm[r]);
                alpha[r] = __expf(Mx[r] - nM);
                Mx[r] = nM;
                ps[r] = 0.f;
            }
            #pragma unroll
            for (int c = 0; c < 4; ++c)
                #pragma unroll
                for (int r = 0; r < 4; ++r) {
                    float p = __expf(S[c][r] - Mx[r]);
                    S[c][r] = p;
                    ps[r] += p;
                }
            #pragma unroll
            for (int r = 0; r < 4; ++r) {
                float v = ps[r];
                v += __shfl_xor(v, 1, 64);
                v += __shfl_xor(v, 2, 64);
                v += __shfl_xor(v, 4, 64);
                v += __shfl_xor(v, 8, 64);
                L[r] = L[r] * alpha[r] + v;
            }
            #pragma unroll
            for (int c = 0; c < 4; ++c)
                #pragma unroll
                for (int r = 0; r < 4; ++r)
                    O[c][r] *= alpha[r];

            #pragma unroll
            for (int c = 0; c < 4; ++c)
                #pragma unroll
                for (int r = 0; r < 4; ++r)
                    Ps[wave * 16 + quad * 4 + r][c * 16 + l16] = (__bf16)S[c][r];
            __syncthreads();

            bf16x8 ap0 = *(const bf16x8*)&Ps[wave * 16 + l16][quad * 8];
            bf16x8 ap1 = *(const bf16x8*)&Ps[wave * 16 + l16][32 + quad * 8];
            #pragma unroll
            for (int c = 0; c < 4; ++c) {
                bf16x8 bv0 = *(const bf16x8*)&Vt[c * 16 + l16][quad * 8];
                bf16x8 bv1 = *(const bf16x8*)&Vt[c * 16 + l16][32 + quad * 8];
                O[c] = __builtin_amdgcn_mfma_f32_16x16x32_bf16(ap0, bv0, O[c], 0, 0, 0);
                O[c] = __builtin_amdgcn_mfma_f32_16x16x32_bf16(ap1, bv1, O[c], 0, 0, 0);
            }
        }

        #pragma unroll
        for (int c = 0; c < 4; ++c) {
            int d = h * 64 + c * 16 + l16;
            #pragma unroll
            for (int r = 0; r < 4; ++r) {
                int qrow = qs + qc + wave * 16 + quad * 4 + r;
                if (qrow < qe) {
                    size_t off = (size_t)qrow * HID + d;
                    Out[off] = (__bf16)((float)Vres[off] + O[c][r] / L[r]);
                }
            }
        }
    }
}

// ------------------------------ launcher -----------------------------------
extern "C" void kernel_launch(void* const* d_in, const int* in_sizes, int n_in,
                              void* d_out, int out_size, void* d_ws, size_t ws_size,
                              hipStream_t stream) {
    (void)in_sizes; (void)n_in; (void)out_size; (void)ws_size;

    const float* h_head = (const float*)d_in[0];
    const float* h_tail = (const float*)d_in[1];
    const int* batch_head = (const int*)d_in[2];
    const int* batch_tail = (const int*)d_in[3];
    const float* map_w = (const float*)d_in[4];
    const float* map_b = (const float*)d_in[5];
    const float* q1_w = (const float*)d_in[6];
    const float* q1_b = (const float*)d_in[7];
    const float* k1_w = (const float*)d_in[8];
    const float* k1_b = (const float*)d_in[9];
    const float* v1_w = (const float*)d_in[10];
    const float* v1_b = (const float*)d_in[11];
    const float* q2_w = (const float*)d_in[12];
    const float* q2_b = (const float*)d_in[13];
    const float* k2_w = (const float*)d_in[14];
    const float* k2_b = (const float*)d_in[15];
    const float* v2_w = (const float*)d_in[16];
    const float* v2_b = (const float*)d_in[17];
    const float* d1_w = (const float*)d_in[18];
    const float* d1_b = (const float*)d_in[19];
    const float* d2_w = (const float*)d_in[20];
    const float* d2_b = (const float*)d_in[21];

    float* out = (float*)d_out;

    const size_t SZ = (size_t)NTOK * HID;
    char* ws = (char*)d_ws;
    int* ranges = (int*)ws;                           // 1 KB
    __bf16* qh   = (__bf16*)(ws + 1024);
    __bf16* kh   = qh  + SZ;
    __bf16* vh   = kh  + SZ;
    __bf16* qt   = vh  + SZ;
    __bf16* kt   = qt  + SZ;
    __bf16* vt   = kt  + SZ;
    __bf16* ctxh = vt  + SZ;
    __bf16* ctxt = ctxh + SZ;
    __bf16* q1T  = ctxt + SZ;                         // [512][512] each
    __bf16* k1T  = q1T + 512 * 512;
    __bf16* v1T  = k1T + 512 * 512;
    __bf16* q2T  = v1T + 512 * 512;
    __bf16* k2T  = q2T + 512 * 512;
    __bf16* v2T  = k2T + 512 * 512;
    __bf16* d1T  = v2T + 512 * 512;
    __bf16* d2T  = d1T + 512 * 512;
    __bf16* hh_bf  = d2T + 512 * 512;                 // [4096][384]
    __bf16* ht_bf  = hh_bf + (size_t)NTOK * KHEAD;    // [4096][512]
    __bf16* map_bf = ht_bf + SZ;                      // [384][512]
    __bf16* fwqT   = map_bf + 384 * 512;              // [512][384] each
    __bf16* fwkT   = fwqT + 512 * KHEAD;
    __bf16* fwvT   = fwkT + 512 * KHEAD;
    float*  fb     = (float*)(fwvT + 512 * KHEAD);    // [3][512]
    float*  zbuf   = fb + 3 * 512;                    // [512]

    // 1) prep: conversions, ranges, fused biases, zero buffer
    prep_inputs<<<dim3(512, 1, 3), dim3(256), 0, stream>>>(
        h_head, h_tail, batch_head, batch_tail,
        map_w, map_b, q1_w, q1_b, k1_w, k1_b, v1_w, v1_b,
        hh_bf, ht_bf, map_bf, fb, zbuf, ranges);

    // 2) transpose 8 weights to bf16 WT
    Trans8 tj;
    const float* wsrc[8] = {q1_w, k1_w, v1_w, q2_w, k2_w, v2_w, d1_w, d2_w};
    __bf16* wdst[8] = {q1T, k1T, v1T, q2T, k2T, v2T, d1T, d2T};
    for (int i = 0; i < 8; ++i) { tj.src[i] = wsrc[i]; tj.dst[i] = wdst[i]; }
    transpose_weights<<<dim3(8, 8, 8), dim3(256), 0, stream>>>(tj);

    // 3) fused head weights: FWT_x[n][k] = sum_j x1T[n][j] * map_bf[k][j]
    //    (= (map_w @ x1_w)^T), M=512, N=384, K=512
    {
        GemmJobs j = {};
        j.A[0] = q1T; j.W[0] = map_bf; j.bias[0] = zbuf; j.C[0] = fwqT; j.Kp[0] = 512; j.ldC[0] = KHEAD;
        j.A[1] = k1T; j.W[1] = map_bf; j.bias[1] = zbuf; j.C[1] = fwkT; j.Kp[1] = 512; j.ldC[1] = KHEAD;
        j.A[2] = v1T; j.W[2] = map_bf; j.bias[2] = zbuf; j.C[2] = fwvT; j.Kp[2] = 512; j.ldC[2] = KHEAD;
        gemm128<__bf16><<<dim3(3, 4, 3), dim3(256), 0, stream>>>(j);
    }

    // 4) all six projections in one dispatch
    {
        GemmJobs j = {};
        j.A[0] = hh_bf; j.W[0] = fwqT; j.bias[0] = fb;       j.C[0] = qh; j.Kp[0] = KHEAD; j.ldC[0] = 512;
        j.A[1] = hh_bf; j.W[1] = fwkT; j.bias[1] = fb + 512; j.C[1] = kh; j.Kp[1] = KHEAD; j.ldC[1] = 512;
        j.A[2] = hh_bf; j.W[2] = fwvT; j.bias[2] = fb + 1024;j.C[2] = vh; j.Kp[2] = KHEAD; j.ldC[2] = 512;
        j.A[3] = ht_bf; j.W[3] = q2T;  j.bias[3] = q2_b;     j.C[3] = qt; j.Kp[3] = 512;   j.ldC[3] = 512;
        j.A[4] = ht_bf; j.W[4] = k2T;  j.bias[4] = k2_b;     j.C[4] = kt; j.Kp[4] = 512;   j.ldC[4] = 512;
        j.A[5] = ht_bf; j.W[5] = v2T;  j.bias[5] = v2_b;     j.C[5] = vt; j.Kp[5] = 512;   j.ldC[5] = 512;
        gemm128<__bf16><<<dim3(4, 32, 6), dim3(256), 0, stream>>>(j);
    }

    // 5) attention (both sides)
    attn_mfma<<<dim3(8, 64, 2), dim3(256), 0, stream>>>(
        qh, kt, vh, vt,
        qt, kh, vt, vh,
        ranges, ctxh, ctxt, NTOK, NTOK);

    // 6) output projections (fp32 into d_out)
    {
        GemmJobs j = {};
        j.A[0] = ctxh; j.W[0] = d1T; j.bias[0] = d1_b; j.C[0] = out;      j.Kp[0] = 512; j.ldC[0] = 512;
        j.A[1] = ctxt; j.W[1] = d2T; j.bias[1] = d2_b; j.C[1] = out + SZ; j.Kp[1] = 512; j.ldC[1] = 512;
        gemm128<float><<<dim3(4, 32, 2), dim3(256), 0, stream>>>(j);
    }
}

// Round 7
// 186.658 us; speedup vs baseline: 1.9498x; 1.9498x over previous
//
#include <hip/hip_runtime.h>
#include <hip/hip_bf16.h>
#include <math.h>

// ---------------------------------------------------------------------------
// CrossModalityMultiHeadAttention  (MI355X / gfx950)
// Round 7: round-5 structure (global_load_lds staging) +
//   - DOUBLE-BUFFERED LDS in gemm128: loads for tile i+1 issued after the
//     barrier, fly across the MFMA section; barrier drains year-old loads
//   - XOR-swizzled k-chunk mapping: ds_read_b128 frag reads uniform across
//     bank quads (2-way = free); coalescing preserved
//   - round-6's register-prefetch + algebraic map-fold REVERTED (regressed:
//     120us/dispatch, 1.38M LDS conflicts)
// Dispatches: prep, transpose(9), gemm[map+qkv-tail z=4], gemm[qkv-head z=3],
//             attn(z=2), gemm[out z=2] = 6 total
// ---------------------------------------------------------------------------

typedef __bf16 bf16x8 __attribute__((ext_vector_type(8)));
typedef float  f32x4  __attribute__((ext_vector_type(4)));

#define HID 512
#define NTOK 4096

#define AS1(p) ((const __attribute__((address_space(1))) void*)(p))
#define AS3(p) ((__attribute__((address_space(3))) void*)(p))

// --------------------------- input prep ------------------------------------
__global__ __launch_bounds__(256) void prep_inputs(
    const float* __restrict__ h_head, const float* __restrict__ h_tail,
    const int* __restrict__ bh, const int* __restrict__ bt,
    __bf16* __restrict__ hh_bf, __bf16* __restrict__ ht_bf,
    int* __restrict__ ranges)
{
    const int q = blockIdx.x, z = blockIdx.z, tid = threadIdx.x;

    if (z == 0) {
        if (q == 0 && tid < 128) {
            int b = tid & 63;
            const int* arr = (tid < 64) ? bh : bt;
            int base = (tid < 64) ? 0 : 128;
            int lo = 0, hi = NTOK;
            while (lo < hi) { int mid = (lo + hi) >> 1; if (arr[mid] < b) lo = mid + 1; else hi = mid; }
            int start = lo;
            lo = 0; hi = NTOK;
            while (lo < hi) { int mid = (lo + hi) >> 1; if (arr[mid] <= b) lo = mid + 1; else hi = mid; }
            ranges[base + b] = start;
            ranges[base + 64 + b] = lo;
        }
        // head: 8 rows x 40 chunks (src 300 cols, dst 320)
        for (int idx = tid; idx < 8 * 40; idx += 256) {
            int r   = q * 8 + idx / 40;
            int col = (idx % 40) * 8;
            bf16x8 v;
            if (col + 8 <= 300) {
                float4 f0 = *(const float4*)&h_head[(size_t)r * 300 + col];
                float4 f1 = *(const float4*)&h_head[(size_t)r * 300 + col + 4];
                v[0]=(__bf16)f0.x; v[1]=(__bf16)f0.y; v[2]=(__bf16)f0.z; v[3]=(__bf16)f0.w;
                v[4]=(__bf16)f1.x; v[5]=(__bf16)f1.y; v[6]=(__bf16)f1.z; v[7]=(__bf16)f1.w;
            } else if (col < 300) {  // col == 296: 4 valid + 4 pad
                float4 f0 = *(const float4*)&h_head[(size_t)r * 300 + col];
                v[0]=(__bf16)f0.x; v[1]=(__bf16)f0.y; v[2]=(__bf16)f0.z; v[3]=(__bf16)f0.w;
                v[4]=(__bf16)0.f; v[5]=(__bf16)0.f; v[6]=(__bf16)0.f; v[7]=(__bf16)0.f;
            } else {
                #pragma unroll
                for (int j = 0; j < 8; ++j) v[j] = (__bf16)0.f;
            }
            *(bf16x8*)&hh_bf[(size_t)r * 320 + col] = v;
        }
    } else {
        for (int idx = tid; idx < 8 * 64; idx += 256) {
            int r   = q * 8 + (idx >> 6);
            int col = (idx & 63) * 8;
            float4 f0 = *(const float4*)&h_tail[(size_t)r * 512 + col];
            float4 f1 = *(const float4*)&h_tail[(size_t)r * 512 + col + 4];
            bf16x8 v;
            v[0]=(__bf16)f0.x; v[1]=(__bf16)f0.y; v[2]=(__bf16)f0.z; v[3]=(__bf16)f0.w;
            v[4]=(__bf16)f1.x; v[5]=(__bf16)f1.y; v[6]=(__bf16)f1.z; v[7]=(__bf16)f1.w;
            *(bf16x8*)&ht_bf[(size_t)r * 512 + col] = v;
        }
    }
}

// --------------------------- weight transpose ------------------------------
// W[K][512] fp32 -> WT[512][ldT] bf16 (rows zero-padded K..ldT).
struct TransJobs {
    const float* src[9];
    __bf16*      dst[9];
    int          K[9];
    int          ldT[9];
};

__global__ __launch_bounds__(256) void transpose_weights(TransJobs tj) {
    const int z = blockIdx.z;
    const float* src = tj.src[z];
    __bf16* dst = tj.dst[z];
    const int K = tj.K[z], ldT = tj.ldT[z];
    const int tk = blockIdx.y * 64;
    const int tn = blockIdx.x * 64;
    if (tk >= ldT) return;

    __shared__ __bf16 T[64][72];
    const int tid = threadIdx.x;
    const int r0 = tid >> 4;
    const int c0 = (tid & 15) * 4;
    #pragma unroll
    for (int i = 0; i < 4; ++i) {
        int k = tk + r0 + i * 16;
        float4 v = (k < K) ? *(const float4*)&src[(size_t)k * 512 + tn + c0]
                           : float4{0.f, 0.f, 0.f, 0.f};
        T[r0 + i * 16][c0 + 0] = (__bf16)v.x;
        T[r0 + i * 16][c0 + 1] = (__bf16)v.y;
        T[r0 + i * 16][c0 + 2] = (__bf16)v.z;
        T[r0 + i * 16][c0 + 3] = (__bf16)v.w;
    }
    __syncthreads();

    const int n  = tid >> 2;
    const int kk = (tid & 3) * 16;
    bf16x8 o0, o1;
    #pragma unroll
    for (int j = 0; j < 8; ++j) { o0[j] = T[kk + j][n]; o1[j] = T[kk + 8 + j][n]; }
    __bf16* dp = dst + (size_t)(tn + n) * ldT + tk + kk;
    *(bf16x8*)dp       = o0;
    *(bf16x8*)(dp + 8) = o1;
}

// ------------------------------ GEMM 128x128 -------------------------------
// C = A[4096,Kp]bf16 @ WT[512,Kp]bf16^T + bias; z = job select.
// 256 thr = 4 waves (2x2), each wave 64x64 (4x4 16x16x32 frags).
// Double-buffered global_load_lds: tile i+1's loads issued AFTER the barrier
// guarding tile i, so they overlap the full ds_read+MFMA section and the next
// barrier's vmcnt(0) drain waits on nearly-complete loads.
// LDS layout: [128][32] with k-chunk XOR swizzle pos = kc ^ ((row>>1)&3)
// (applied on the lane->global mapping; frag reads use the matching swizzle)
// -> ds_read_b128 uniform over all 8 bank quads.
struct GemmJobs {
    const __bf16* A[4];
    const __bf16* W[4];
    const float*  bias[4];
    void*         C[4];
    int           Kp[4];
};

template <typename TC>
__global__ __launch_bounds__(256) void gemm128(GemmJobs jobs) {
    __shared__ __align__(16) __bf16 As[2][4096];   // 2 x [128][32]
    __shared__ __align__(16) __bf16 Bs[2][4096];

    const int z = blockIdx.z;
    const __bf16* A    = jobs.A[z];
    const __bf16* W    = jobs.W[z];
    const float*  bias = jobs.bias[z];
    TC*           C    = (TC*)jobs.C[z];
    const int     Kp   = jobs.Kp[z];

    const int tid  = threadIdx.x;
    const int wave = tid >> 6;
    const int lane = tid & 63;
    const int quad = lane >> 4;
    const int l16  = lane & 15;
    const int wy   = wave >> 1;
    const int wx   = wave & 1;
    const int rowBase = blockIdx.y * 128;
    const int colBase = blockIdx.x * 128;

    // staging: thread t owns row t>>2 (and row+64 via second load),
    // k-chunk XOR-swizzled so LDS chunk (row*4 + t&3) holds kc = (t&3)^swz
    const int s_row = tid >> 2;
    const int s_kc  = ((tid & 3) ^ ((s_row >> 1) & 3)) * 8;

    const __bf16* gA = A + (size_t)(rowBase + s_row) * Kp + s_kc;
    const __bf16* gB = W + (size_t)(colBase + s_row) * Kp + s_kc;
    const int waveOff = wave * 512;

    f32x4 acc[4][4] = {};
    const int nk = Kp >> 5;

    // preload tile 0 -> buffer 0
    __builtin_amdgcn_global_load_lds(AS1(gA),                   AS3(&As[0][waveOff]),        16, 0, 0);
    __builtin_amdgcn_global_load_lds(AS1(gA + (size_t)64 * Kp), AS3(&As[0][2048 + waveOff]), 16, 0, 0);
    __builtin_amdgcn_global_load_lds(AS1(gB),                   AS3(&Bs[0][waveOff]),        16, 0, 0);
    __builtin_amdgcn_global_load_lds(AS1(gB + (size_t)64 * Kp), AS3(&Bs[0][2048 + waveOff]), 16, 0, 0);

    for (int i = 0; i < nk; ++i) {
        const int cur = i & 1;
        __syncthreads();   // drains tile i's loads (old); prev reads of buf[cur^1] done

        if (i + 1 < nk) {  // issue tile i+1 into the other buffer; flies over MFMA below
            const int kt = (i + 1) * 32;
            const int nx = cur ^ 1;
            __builtin_amdgcn_global_load_lds(AS1(gA + kt),                   AS3(&As[nx][waveOff]),        16, 0, 0);
            __builtin_amdgcn_global_load_lds(AS1(gA + kt + (size_t)64 * Kp), AS3(&As[nx][2048 + waveOff]), 16, 0, 0);
            __builtin_amdgcn_global_load_lds(AS1(gB + kt),                   AS3(&Bs[nx][waveOff]),        16, 0, 0);
            __builtin_amdgcn_global_load_lds(AS1(gB + kt + (size_t)64 * Kp), AS3(&Bs[nx][2048 + waveOff]), 16, 0, 0);
        }

        bf16x8 ar[4], br[4];
        #pragma unroll
        for (int ii = 0; ii < 4; ++ii) {
            const int ra = wy * 64 + ii * 16 + l16;
            ar[ii] = *(const bf16x8*)&As[cur][ra * 32 + ((quad ^ ((ra >> 1) & 3)) << 3)];
        }
        #pragma unroll
        for (int jj = 0; jj < 4; ++jj) {
            const int rb = wx * 64 + jj * 16 + l16;
            br[jj] = *(const bf16x8*)&Bs[cur][rb * 32 + ((quad ^ ((rb >> 1) & 3)) << 3)];
        }
        #pragma unroll
        for (int ii = 0; ii < 4; ++ii)
            #pragma unroll
            for (int jj = 0; jj < 4; ++jj)
                acc[ii][jj] = __builtin_amdgcn_mfma_f32_16x16x32_bf16(ar[ii], br[jj], acc[ii][jj], 0, 0, 0);
    }

    // epilogue: C/D layout col=l16, row=quad*4+reg
    #pragma unroll
    for (int jj = 0; jj < 4; ++jj) {
        int col = colBase + wx * 64 + jj * 16 + l16;
        float bv = bias[col];
        #pragma unroll
        for (int ii = 0; ii < 4; ++ii) {
            #pragma unroll
            for (int r = 0; r < 4; ++r) {
                int row = rowBase + wy * 64 + ii * 16 + quad * 4 + r;
                C[(size_t)row * HID + col] = (TC)(acc[ii][jj][r] + bv);
            }
        }
    }
}

// ------------------------- MFMA flash attention ----------------------------
// grid = (head 8, batch 64, side 2). side 0: head-q x tail-k; side 1: swap.
__global__ __launch_bounds__(256) void attn_mfma(
    const __bf16* __restrict__ Q0, const __bf16* __restrict__ K0,
    const __bf16* __restrict__ Vr0, const __bf16* __restrict__ Vc0,
    const __bf16* __restrict__ Q1, const __bf16* __restrict__ K1,
    const __bf16* __restrict__ Vr1, const __bf16* __restrict__ Vc1,
    const int* __restrict__ ranges,
    __bf16* __restrict__ O0, __bf16* __restrict__ O1,
    int Nq, int Nk)
{
    __shared__ __align__(16) __bf16 Qs[64][72];
    __shared__ __align__(16) __bf16 Ks[64][72];
    __shared__ __align__(16) __bf16 Vt[64][72];   // [dim][key]
    __shared__ __align__(16) __bf16 Ps[64][72];   // [query][key]

    const int z = blockIdx.z;
    const __bf16* Q    = z ? Q1 : Q0;
    const __bf16* Kg   = z ? K1 : K0;
    const __bf16* Vres = z ? Vr1 : Vr0;
    const __bf16* Vctx = z ? Vc1 : Vc0;
    __bf16* Out        = z ? O1 : O0;
    const int* qstart  = z ? ranges + 128 : ranges;
    const int* qend    = z ? ranges + 192 : ranges + 64;
    const int* kstart  = z ? ranges       : ranges + 128;
    const int* kend    = z ? ranges + 64  : ranges + 192;

    const int h = blockIdx.x, b = blockIdx.y;
    const int qs = qstart[b], qe = qend[b];
    const int ts = kstart[b], te = kend[b];
    const int nq = qe - qs, nk = te - ts;
    if (nq <= 0) return;

    const int tid  = threadIdx.x;
    const int wave = tid >> 6;
    const int lane = tid & 63;
    const int quad = lane >> 4;
    const int l16  = lane & 15;
    const int srow = tid >> 2;
    const int scol = (tid & 3) * 16;

    if (nk <= 0) {
        float* meanv = (float*)Qs;
        if (tid < 64) {
            float s = 0.f;
            for (int m = 0; m < Nk; ++m)
                s += (float)Vctx[(size_t)m * HID + h * 64 + tid];
            meanv[tid] = s / (float)Nk;
        }
        __syncthreads();
        int d = tid & 63;
        for (int r = qs + (tid >> 6); r < qe; r += 4) {
            size_t off = (size_t)r * HID + h * 64 + d;
            Out[off] = (__bf16)((float)Vres[off] + meanv[d]);
        }
        return;
    }

    for (int qc = 0; qc < nq; qc += 64) {
        __syncthreads();
        {
            int qg = min(qs + qc + srow, Nq - 1);
            const __bf16* src = Q + (size_t)qg * HID + h * 64 + scol;
            *(bf16x8*)&Qs[srow][scol]     = *(const bf16x8*)src;
            *(bf16x8*)&Qs[srow][scol + 8] = *(const bf16x8*)(src + 8);
        }
        __syncthreads();
        bf16x8 aq0 = *(const bf16x8*)&Qs[wave * 16 + l16][quad * 8];
        bf16x8 aq1 = *(const bf16x8*)&Qs[wave * 16 + l16][32 + quad * 8];

        f32x4 O[4] = {};
        float Mx[4], L[4];
        #pragma unroll
        for (int r = 0; r < 4; ++r) { Mx[r] = -__builtin_inff(); L[r] = 0.f; }

        for (int kc = 0; kc < nk; kc += 64) {
            __syncthreads();
            {
                int kg = min(ts + kc + srow, Nk - 1);
                const __bf16* ksrc = Kg + (size_t)kg * HID + h * 64 + scol;
                *(bf16x8*)&Ks[srow][scol]     = *(const bf16x8*)ksrc;
                *(bf16x8*)&Ks[srow][scol + 8] = *(const bf16x8*)(ksrc + 8);
                const __bf16* vsrc = Vctx + (size_t)kg * HID + h * 64 + scol;
                bf16x8 v0 = *(const bf16x8*)vsrc;
                bf16x8 v1 = *(const bf16x8*)(vsrc + 8);
                #pragma unroll
                for (int j = 0; j < 8; ++j) {
                    Vt[scol + j][srow]     = v0[j];
                    Vt[scol + 8 + j][srow] = v1[j];
                }
            }
            __syncthreads();

            f32x4 S[4] = {};
            #pragma unroll
            for (int c = 0; c < 4; ++c) {
                bf16x8 bk0 = *(const bf16x8*)&Ks[c * 16 + l16][quad * 8];
                bf16x8 bk1 = *(const bf16x8*)&Ks[c * 16 + l16][32 + quad * 8];
                S[c] = __builtin_amdgcn_mfma_f32_16x16x32_bf16(aq0, bk0, S[c], 0, 0, 0);
                S[c] = __builtin_amdgcn_mfma_f32_16x16x32_bf16(aq1, bk1, S[c], 0, 0, 0);
            }

            #pragma unroll
            for (int c = 0; c < 4; ++c) {
                bool valid = (ts + kc + c * 16 + l16) < te;
                #pragma unroll
                for (int r = 0; r < 4; ++r)
                    S[c][r] = valid ? S[c][r] * 0.125f : -__builtin_inff();
            }

            float cm[4], ps[4], alpha[4];
            #pragma unroll
            for (int r = 0; r < 4; ++r) {
                float v = fmaxf(fmaxf(S[0][r], S[1][r]), fmaxf(S[2][r], S[3][r]));
                v = fmaxf(v, __shfl_xor(v, 1, 64));
                v = fmaxf(v, __shfl_xor(v, 2, 64));
                v = fmaxf(v, __shfl_xor(v, 4, 64));
                v = fmaxf(v, __shfl_xor(v, 8, 64));
                cm[r] = v;
            }
            #pragma unroll
            for (int r = 0; r < 4; ++r) {
                float nM = fmaxf(Mx[r], cm[r]);
                alpha[r] = __expf(Mx[r] - nM);
                Mx[r] = nM;
                ps[r] = 0.f;
            }
            #pragma unroll
            for (int c = 0; c < 4; ++c)
                #pragma unroll
                for (int r = 0; r < 4; ++r) {
                    float p = __expf(S[c][r] - Mx[r]);
                    S[c][r] = p;
                    ps[r] += p;
                }
            #pragma unroll
            for (int r = 0; r < 4; ++r) {
                float v = ps[r];
                v += __shfl_xor(v, 1, 64);
                v += __shfl_xor(v, 2, 64);
                v += __shfl_xor(v, 4, 64);
                v += __shfl_xor(v, 8, 64);
                L[r] = L[r] * alpha[r] + v;
            }
            #pragma unroll
            for (int c = 0; c < 4; ++c)
                #pragma unroll
                for (int r = 0; r < 4; ++r)
                    O[c][r] *= alpha[r];

            #pragma unroll
            for (int c = 0; c < 4; ++c)
                #pragma unroll
                for (int r = 0; r < 4; ++r)
                    Ps[wave * 16 + quad * 4 + r][c * 16 + l16] = (__bf16)S[c][r];
            __syncthreads();

            bf16x8 ap0 = *(const bf16x8*)&Ps[wave * 16 + l16][quad * 8];
            bf16x8 ap1 = *(const bf16x8*)&Ps[wave * 16 + l16][32 + quad * 8];
            #pragma unroll
            for (int c = 0; c < 4; ++c) {
                bf16x8 bv0 = *(const bf16x8*)&Vt[c * 16 + l16][quad * 8];
                bf16x8 bv1 = *(const bf16x8*)&Vt[c * 16 + l16][32 + quad * 8];
                O[c] = __builtin_amdgcn_mfma_f32_16x16x32_bf16(ap0, bv0, O[c], 0, 0, 0);
                O[c] = __builtin_amdgcn_mfma_f32_16x16x32_bf16(ap1, bv1, O[c], 0, 0, 0);
            }
        }

        #pragma unroll
        for (int c = 0; c < 4; ++c) {
            int d = h * 64 + c * 16 + l16;
            #pragma unroll
            for (int r = 0; r < 4; ++r) {
                int qrow = qs + qc + wave * 16 + quad * 4 + r;
                if (qrow < qe) {
                    size_t off = (size_t)qrow * HID + d;
                    Out[off] = (__bf16)((float)Vres[off] + O[c][r] / L[r]);
                }
            }
        }
    }
}

// ------------------------------ launcher -----------------------------------
extern "C" void kernel_launch(void* const* d_in, const int* in_sizes, int n_in,
                              void* d_out, int out_size, void* d_ws, size_t ws_size,
                              hipStream_t stream) {
    (void)in_sizes; (void)n_in; (void)out_size; (void)ws_size;

    const float* h_head = (const float*)d_in[0];
    const float* h_tail = (const float*)d_in[1];
    const int* batch_head = (const int*)d_in[2];
    const int* batch_tail = (const int*)d_in[3];
    const float* map_w = (const float*)d_in[4];
    const float* map_b = (const float*)d_in[5];
    const float* q1_w = (const float*)d_in[6];
    const float* q1_b = (const float*)d_in[7];
    const float* k1_w = (const float*)d_in[8];
    const float* k1_b = (const float*)d_in[9];
    const float* v1_w = (const float*)d_in[10];
    const float* v1_b = (const float*)d_in[11];
    const float* q2_w = (const float*)d_in[12];
    const float* q2_b = (const float*)d_in[13];
    const float* k2_w = (const float*)d_in[14];
    const float* k2_b = (const float*)d_in[15];
    const float* v2_w = (const float*)d_in[16];
    const float* v2_b = (const float*)d_in[17];
    const float* d1_w = (const float*)d_in[18];
    const float* d1_b = (const float*)d_in[19];
    const float* d2_w = (const float*)d_in[20];
    const float* d2_b = (const float*)d_in[21];

    float* out = (float*)d_out;

    const size_t SZ = (size_t)NTOK * HID;
    char* ws = (char*)d_ws;
    int* ranges = (int*)ws;                         // 1 KB
    __bf16* hh   = (__bf16*)(ws + 1024);
    __bf16* qh   = hh  + SZ;
    __bf16* kh   = qh  + SZ;
    __bf16* vh   = kh  + SZ;
    __bf16* qt   = vh  + SZ;
    __bf16* kt   = qt  + SZ;
    __bf16* vt   = kt  + SZ;
    __bf16* ctxh = vt  + SZ;
    __bf16* ctxt = ctxh + SZ;
    __bf16* mapT = ctxt + SZ;                       // [512][320]
    __bf16* q1T  = mapT + 512 * 320;                // [512][512] each
    __bf16* k1T  = q1T + 512 * 512;
    __bf16* v1T  = k1T + 512 * 512;
    __bf16* q2T  = v1T + 512 * 512;
    __bf16* k2T  = q2T + 512 * 512;
    __bf16* v2T  = k2T + 512 * 512;
    __bf16* d1T  = v2T + 512 * 512;
    __bf16* d2T  = d1T + 512 * 512;
    __bf16* hh_bf = d2T + 512 * 512;                // [4096][320]
    __bf16* ht_bf = hh_bf + (size_t)NTOK * 320;     // [4096][512]

    // prep: convert activations + ranges
    prep_inputs<<<dim3(512, 1, 2), dim3(256), 0, stream>>>(
        h_head, h_tail, batch_head, batch_tail, hh_bf, ht_bf, ranges);

    // transpose all weights
    TransJobs tj;
    tj.src[0] = map_w; tj.dst[0] = mapT; tj.K[0] = 300; tj.ldT[0] = 320;
    const float* wsrc[8] = {q1_w, k1_w, v1_w, q2_w, k2_w, v2_w, d1_w, d2_w};
    __bf16* wdst[8] = {q1T, k1T, v1T, q2T, k2T, v2T, d1T, d2T};
    for (int i = 0; i < 8; ++i) {
        tj.src[i + 1] = wsrc[i]; tj.dst[i + 1] = wdst[i];
        tj.K[i + 1] = 512; tj.ldT[i + 1] = 512;
    }
    transpose_weights<<<dim3(8, 8, 9), dim3(256), 0, stream>>>(tj);

    // GEMM group 1: map + qkv-tail (inputs only)
    {
        GemmJobs j;
        j.A[0] = hh_bf; j.W[0] = mapT; j.bias[0] = map_b; j.C[0] = hh; j.Kp[0] = 320;
        j.A[1] = ht_bf; j.W[1] = q2T; j.bias[1] = q2_b; j.C[1] = qt; j.Kp[1] = 512;
        j.A[2] = ht_bf; j.W[2] = k2T; j.bias[2] = k2_b; j.C[2] = kt; j.Kp[2] = 512;
        j.A[3] = ht_bf; j.W[3] = v2T; j.bias[3] = v2_b; j.C[3] = vt; j.Kp[3] = 512;
        gemm128<__bf16><<<dim3(4, 32, 4), dim3(256), 0, stream>>>(j);
    }
    // GEMM group 2: qkv-head (depends on hh)
    {
        GemmJobs j;
        j.A[0] = hh; j.W[0] = q1T; j.bias[0] = q1_b; j.C[0] = qh; j.Kp[0] = 512;
        j.A[1] = hh; j.W[1] = k1T; j.bias[1] = k1_b; j.C[1] = kh; j.Kp[1] = 512;
        j.A[2] = hh; j.W[2] = v1T; j.bias[2] = v1_b; j.C[2] = vh; j.Kp[2] = 512;
        j.A[3] = hh; j.W[3] = v1T; j.bias[3] = v1_b; j.C[3] = vh; j.Kp[3] = 512;
        gemm128<__bf16><<<dim3(4, 32, 3), dim3(256), 0, stream>>>(j);
    }

    // attention (both sides, one dispatch)
    attn_mfma<<<dim3(8, 64, 2), dim3(256), 0, stream>>>(
        qh, kt, vh, vt,
        qt, kh, vt, vh,
        ranges, ctxh, ctxt, NTOK, NTOK);

    // GEMM group 3: output projections (fp32 into d_out)
    {
        GemmJobs j;
        j.A[0] = ctxh; j.W[0] = d1T; j.bias[0] = d1_b; j.C[0] = out;      j.Kp[0] = 512;
        j.A[1] = ctxt; j.W[1] = d2T; j.bias[1] = d2_b; j.C[1] = out + SZ; j.Kp[1] = 512;
        j.A[2] = ctxt; j.W[2] = d2T; j.bias[2] = d2_b; j.C[2] = out + SZ; j.Kp[2] = 512;
        j.A[3] = ctxt; j.W[3] = d2T; j.bias[3] = d2_b; j.C[3] = out + SZ; j.Kp[3] = 512;
        gemm128<float><<<dim3(4, 32, 2), dim3(256), 0, stream>>>(j);
    }
}